// Round 14
// baseline (670.742 us; speedup 1.0000x reference)
//
#include <hip/hip_runtime.h>

#define N_NODES 50000
#define N_EDGES 800000
#define N_GROUPS 12500        // 4 nodes per group
#define ELL_W 64              // u16 slots per node; deg+1 max ~37
#define F_IN 56
#define F_PAD 64
#define F_OUT 256
#define NB 16                 // nodes per k_final block
#define SEG_SZ 6250           // dst segment per XCD for k_fill
#define ZROW N_NODES          // always-zero row in each slice
#define NSL 4                 // feature slices
#define ROW_F 16              // floats per row per slice (64 B)
#define SL_STRIDE ((size_t)(N_NODES + 1) * ROW_F)  // floats per slice array
#define HOP_BLOCKS 624        // 8 XCD-slots x 78, fully co-resident
#define WAVES_PER_SLICE 624   // 156 blocks x 4 waves

typedef float f32x4 __attribute__((ext_vector_type(4)));

// ---- fill: XCD-segmented append into per-node u16 ELL ----------------------
// grid 512 (co-resident) so bid%8 -> XCD stays stable; each XCD writes only
// its 800KB ELL window.

__global__ __launch_bounds__(256) void k_fill(const int* __restrict__ ei,
                                              int* __restrict__ cnt,
                                              unsigned short* __restrict__ ell) {
  int seg = blockIdx.x & 7;
  int chunk = blockIdx.x >> 3;
  int nchunks = gridDim.x >> 3;
  int stride = nchunks * blockDim.x;
  for (int e = chunk * blockDim.x + threadIdx.x; e < N_EDGES; e += stride) {
    int d = ei[N_EDGES + e];
    if (d / SEG_SZ == seg) {
      int s = ei[e];
      int pos = atomicAdd(&cnt[d], 1);
      ell[((size_t)d << 6) + pos] = (unsigned short)s;
    }
  }
}

// ---- prep: self-loop slot, deg, ideg, sqd, dinv ----------------------------

__global__ void k_prep(const int* __restrict__ cnt, int* __restrict__ deg,
                       unsigned short* __restrict__ ell, float* __restrict__ dinv,
                       float* __restrict__ ideg, float* __restrict__ sqd) {
  int i = blockIdx.x * blockDim.x + threadIdx.x;
  if (i >= N_NODES) return;
  int c = cnt[i];
  int d = c + 1;
  ell[((size_t)i << 6) + c] = (unsigned short)i;  // self loop
  deg[i] = d;
  float fc = (float)d;
  dinv[i] = rsqrtf(fc);
  ideg[i] = 1.0f / fc;
  sqd[i]  = sqrtf(fc);
}

// ---- feature init into sliced layout; zero rows in BOTH buffers ------------

__global__ void k_loadx(const float* __restrict__ x, const float* __restrict__ dinv,
                        float* __restrict__ hA, float* __restrict__ hB) {
  int i = blockIdx.x * blockDim.x + threadIdx.x;  // (N+1)*64 threads
  if (i >= (N_NODES + 1) * 64) return;
  int node = i >> 6, f = i & 63;
  int s = f >> 4, fi = f & 15;
  size_t addr = (size_t)s * SL_STRIDE + ((size_t)node << 4) + fi;
  if (node == N_NODES) {            // zero row for pad gathers
    hA[addr] = 0.f;
    hB[addr] = 0.f;
    return;
  }
  float di = dinv[node];
  float v = 0.f;
  if (f < F_IN) v = x[node * F_IN + f] * di;
  else if (f == F_IN) v = di;       // ones column in u-space
  hA[addr] = v;
}

// ---- one hop, slice-pinned: block's slice = (bid&7)>>1 ---------------------
// wave = 4 nodes x 4 edge-subs x 4 fquads; gather = 16 rows x 64B = 1KB/instr;
// unweighted adds; NT dst store keeps the src slice L2-resident on its XCDs.

__global__ __launch_bounds__(256) void k_hop(const float* __restrict__ hA_all,
                                             float* __restrict__ hB_all,
                                             const int* __restrict__ deg,
                                             const unsigned short* __restrict__ ell,
                                             const float* __restrict__ ideg,
                                             float* __restrict__ vsave) {
  int bid = blockIdx.x;
  int xslot = bid & 7;
  int slice = xslot >> 1;
  int ws = ((bid >> 3) << 1) + (xslot & 1);            // 0..155 within slice
  int wv = (ws << 2) + (threadIdx.x >> 6);             // 0..623 within slice
  int lane = threadIdx.x & 63;
  int n2 = lane >> 4, sub = (lane >> 2) & 3, fq = lane & 3;
  const float* __restrict__ hin = hA_all + (size_t)slice * SL_STRIDE;
  float* __restrict__ hout = hB_all + (size_t)slice * SL_STRIDE;
  bool do_v = (vsave != nullptr) && (slice == 3);

  for (int g = wv; g < N_GROUPS; g += WAVES_PER_SLICE) {
    int node = (g << 2) + n2;
    int d = deg[node];                                 // same for 16 lanes
    int dmax = max(d, __shfl_xor(d, 16));              // max over 4 nodes
    dmax = max(dmax, __shfl_xor(dmax, 32));
    int nq = (dmax + 3) >> 2;
    const unsigned short* row = ell + ((size_t)node << 6);
    float4 acc = make_float4(0.f, 0.f, 0.f, 0.f);

#define CH(K, EV, AV)                                                     \
    int ei_##EV = ((c + K) << 2) + sub;                                   \
    int EV = (ei_##EV < d) ? (int)row[ei_##EV] : ZROW;                    \
    float4 AV = *(const float4*)(hin + ((size_t)EV << 4) + (fq << 2));
#define AC(AV) { acc.x += AV.x; acc.y += AV.y; acc.z += AV.z; acc.w += AV.w; }

    int c = 0;
    for (; c + 4 <= nq; c += 4) {          // 4 x 1KB gathers in flight
      CH(0, e0, a0)
      CH(1, e1, a1)
      CH(2, e2, a2)
      CH(3, e3, a3)
      AC(a0) AC(a1) AC(a2) AC(a3)
    }
    for (; c < nq; ++c) {
      CH(0, e0, a0)
      AC(a0)
    }
#undef CH
#undef AC

    // reduce over the 4 edge-subs (lane bits 2,3)
    acc.x += __shfl_xor(acc.x, 4);
    acc.y += __shfl_xor(acc.y, 4);
    acc.z += __shfl_xor(acc.z, 4);
    acc.w += __shfl_xor(acc.w, 4);
    acc.x += __shfl_xor(acc.x, 8);
    acc.y += __shfl_xor(acc.y, 8);
    acc.z += __shfl_xor(acc.z, 8);
    acc.w += __shfl_xor(acc.w, 8);

    float idg = ideg[node];
    acc.x *= idg; acc.y *= idg; acc.z *= idg; acc.w *= idg;

    if (sub == 0) {                        // 16 lanes -> 256B contiguous
      f32x4 av; av.x = acc.x; av.y = acc.y; av.z = acc.z; av.w = acc.w;
      __builtin_nontemporal_store(av,
          (f32x4*)(hout + ((size_t)node << 4) + (fq << 2)));
      if (do_v && fq == 2) vsave[node] = acc.x;   // slice3 fi=8 -> col 56
    }
  }
}

// ---- collapse weights: M = W1W2W3W4; c1=b1'W2W3W4; c2=b2'W3W4; c3=b3'W4+b4

__global__ void k_weights(const float* __restrict__ W1, const float* __restrict__ b1,
                          const float* __restrict__ W2, const float* __restrict__ b2,
                          const float* __restrict__ W3, const float* __restrict__ b3,
                          const float* __restrict__ W4, const float* __restrict__ b4,
                          float* __restrict__ Mw, float* __restrict__ c1,
                          float* __restrict__ c2, float* __restrict__ c3) {
  __shared__ float t1[64], t2[64], t3[64];
  int m = blockIdx.x, tid = threadIdx.x;
  if (m < F_IN) {
    if (tid < 64) {
      float a = 0.f;
      for (int k = 0; k < 64; ++k) a = fmaf(W1[m * 64 + k], W2[k * 64 + tid], a);
      t1[tid] = a;
    }
    __syncthreads();
    if (tid < 64) {
      float a = 0.f;
      for (int k = 0; k < 64; ++k) a = fmaf(t1[k], W3[k * 64 + tid], a);
      t2[tid] = a;
    }
    __syncthreads();
    {
      float a = 0.f;
      for (int k = 0; k < 64; ++k) a = fmaf(t2[k], W4[k * 256 + tid], a);
      Mw[m * 256 + tid] = a;
    }
  } else {
    if (tid < 64) {
      float a = 0.f;
      for (int k = 0; k < 64; ++k) a = fmaf(b1[k], W2[k * 64 + tid], a);
      t1[tid] = a;
    }
    __syncthreads();
    if (tid < 64) {
      float a = 0.f, b = 0.f;
      for (int k = 0; k < 64; ++k) {
        float w3 = W3[k * 64 + tid];
        a = fmaf(t1[k], w3, a);
        b = fmaf(b2[k], w3, b);
      }
      t2[tid] = a; t3[tid] = b;
    }
    __syncthreads();
    {
      float a = 0.f, b = 0.f, c = 0.f;
      for (int k = 0; k < 64; ++k) {
        float w4 = W4[k * 256 + tid];
        a = fmaf(t2[k], w4, a);
        b = fmaf(t3[k], w4, b);
        c = fmaf(b3[k], w4, c);
      }
      c1[tid] = a; c2[tid] = b; c3[tid] = c + b4[tid];
    }
  }
}

// ---- epilogue: out = (sqd*y)@M + v6*c1 + v3*c2 + c3 (sliced y) -------------

__global__ __launch_bounds__(256) void k_final(const float* __restrict__ y,
                                               const float* __restrict__ v3u,
                                               const float* __restrict__ v6u,
                                               const float* __restrict__ sqd,
                                               const float* __restrict__ Mw,
                                               const float* __restrict__ c1,
                                               const float* __restrict__ c2,
                                               const float* __restrict__ c3,
                                               float* __restrict__ out) {
  __shared__ float4 yl[NB][16];
  __shared__ float v3l[NB], v6l[NB];
  int tid = threadIdx.x;
  int j = tid;

  float4 Mreg[14];
#pragma unroll
  for (int k4 = 0; k4 < 14; ++k4) {
    Mreg[k4].x = Mw[(k4 * 4 + 0) * F_OUT + j];
    Mreg[k4].y = Mw[(k4 * 4 + 1) * F_OUT + j];
    Mreg[k4].z = Mw[(k4 * 4 + 2) * F_OUT + j];
    Mreg[k4].w = Mw[(k4 * 4 + 3) * F_OUT + j];
  }
  float C1 = c1[j], C2 = c2[j], C3 = c3[j];

  int n0 = blockIdx.x * NB;
  {                                        // exactly one float4 per thread
    int nn = tid >> 4, q = tid & 15;       // q: 16 fquads across 4 slices
    int s = q >> 2, qq = q & 3;
    float sq = sqd[n0 + nn];
    float4 v = *(const float4*)(y + (size_t)s * SL_STRIDE +
                                ((size_t)(n0 + nn) << 4) + (qq << 2));
    v.x *= sq; v.y *= sq; v.z *= sq; v.w *= sq;
    yl[nn][q] = v;
  }
  if (tid < NB) {
    float sq = sqd[n0 + tid];
    v3l[tid] = v3u[n0 + tid] * sq;
    v6l[tid] = v6u[n0 + tid] * sq;
  }
  __syncthreads();

  float acc[NB];
#pragma unroll
  for (int nn = 0; nn < NB; ++nn)
    acc[nn] = fmaf(v6l[nn], C1, fmaf(v3l[nn], C2, C3));

#pragma unroll
  for (int k4 = 0; k4 < 14; ++k4) {
    float4 mk = Mreg[k4];
#pragma unroll
    for (int nn = 0; nn < NB; ++nn) {
      float4 yv = yl[nn][k4];
      acc[nn] = fmaf(yv.w, mk.w,
                fmaf(yv.z, mk.z,
                fmaf(yv.y, mk.y,
                fmaf(yv.x, mk.x, acc[nn]))));
    }
  }

#pragma unroll
  for (int nn = 0; nn < NB; ++nn)
    out[(size_t)(n0 + nn) * F_OUT + j] = acc[nn];
}

// ---- launch ---------------------------------------------------------------

extern "C" void kernel_launch(void* const* d_in, const int* in_sizes, int n_in,
                              void* d_out, int out_size, void* d_ws, size_t ws_size,
                              hipStream_t stream) {
  const float* x  = (const float*)d_in[0];
  const int*   ei = (const int*)d_in[1];
  const float* W1 = (const float*)d_in[2];
  const float* b1 = (const float*)d_in[3];
  const float* W2 = (const float*)d_in[4];
  const float* b2 = (const float*)d_in[5];
  const float* W3 = (const float*)d_in[6];
  const float* b3 = (const float*)d_in[7];
  const float* W4 = (const float*)d_in[8];
  const float* b4 = (const float*)d_in[9];
  float* out = (float*)d_out;

  char* ws = (char*)d_ws;
  size_t off = 0;
  auto take = [&](size_t bytes) -> void* {
    void* p = ws + off;
    off += (bytes + 255) & ~(size_t)255;
    return p;
  };
  int*            cnt  = (int*)take((size_t)N_NODES * 4);
  int*            deg  = (int*)take((size_t)N_NODES * 4);
  float*          dinv = (float*)take((size_t)N_NODES * 4);
  float*          ideg = (float*)take((size_t)N_NODES * 4);
  float*          sqd  = (float*)take((size_t)N_NODES * 4);
  float*          v3   = (float*)take((size_t)N_NODES * 4);
  float*          v6   = (float*)take((size_t)N_NODES * 4);
  unsigned short* ell  = (unsigned short*)take((size_t)N_NODES * ELL_W * 2); // 6.4 MB
  float*          hA   = (float*)take(SL_STRIDE * NSL * 4);  // 12.8 MB sliced
  float*          hB   = (float*)take(SL_STRIDE * NSL * 4);
  float*          Mw   = (float*)take((size_t)F_IN * F_OUT * 4);
  float*          c1   = (float*)take((size_t)F_OUT * 4);
  float*          c2   = (float*)take((size_t)F_OUT * 4);
  float*          c3   = (float*)take((size_t)F_OUT * 4);

  (void)hipMemsetAsync(cnt, 0, (size_t)N_NODES * 4, stream);
  k_fill<<<512, 256, 0, stream>>>(ei, cnt, ell);
  k_prep<<<(N_NODES + 255) / 256, 256, 0, stream>>>(cnt, deg, ell, dinv, ideg, sqd);
  k_loadx<<<((N_NODES + 1) * 64 + 255) / 256, 256, 0, stream>>>(x, dinv, hA, hB);
  k_weights<<<F_IN + 1, 256, 0, stream>>>(W1, b1, W2, b2, W3, b3, W4, b4, Mw, c1, c2, c3);

  float* src = hA;
  float* dst = hB;
  for (int hop = 1; hop <= 9; ++hop) {
    float* vs = (hop == 3) ? v3 : (hop == 6) ? v6 : nullptr;
    k_hop<<<HOP_BLOCKS, 256, 0, stream>>>(src, dst, deg, ell, ideg, vs);
    float* t = src; src = dst; dst = t;
  }
  k_final<<<N_NODES / NB, 256, 0, stream>>>(src, v3, v6, sqd, Mw, c1, c2, c3, out);
}

// Round 15
// 327.585 us; speedup vs baseline: 2.0475x; 2.0475x over previous
//
#include <hip/hip_runtime.h>

#define N_NODES 50000
#define N_EDGES 800000
#define N_GROUPS 12500      // 4 nodes per group
#define GSLOTS 128          // slots per group
#define F_IN 56
#define F_PAD 64
#define F_OUT 256
#define NB 16               // nodes per k_final block (50000 % 16 == 0)
#define SEG_SZ 6250         // dst segment per XCD for k_fill
#define ZROW N_NODES        // always-zero row in hA/hB
#define PAD_E 0x7FFFFFFF
#define CPAD 16             // gcnt padded to 64B/counter (kills line contention)

typedef float f32x4 __attribute__((ext_vector_type(4)));

// ---- fill: XCD-segmented append; padded counters + 4-edge MLP --------------

__global__ __launch_bounds__(256) void k_fill(const int* __restrict__ ei,
                                              int* __restrict__ gcnt,
                                              int* __restrict__ ellg) {
  int seg = blockIdx.x & 7;
  int chunk = blockIdx.x >> 3;
  int nchunks = gridDim.x >> 3;
  int stride = nchunks * blockDim.x * 4;
  for (int e = (chunk * blockDim.x + threadIdx.x) * 4; e < N_EDGES; e += stride) {
    int4 dd = *(const int4*)(ei + N_EDGES + e);   // 4 dsts, one 16B load
    if (dd.x / SEG_SZ == seg) {
      int s = ei[e];
      int pos = atomicAdd(&gcnt[(dd.x >> 2) * CPAD], 1);
      ellg[((dd.x >> 2) << 7) + pos] = (s << 2) | (dd.x & 3);
    }
    if (dd.y / SEG_SZ == seg) {
      int s = ei[e + 1];
      int pos = atomicAdd(&gcnt[(dd.y >> 2) * CPAD], 1);
      ellg[((dd.y >> 2) << 7) + pos] = (s << 2) | (dd.y & 3);
    }
    if (dd.z / SEG_SZ == seg) {
      int s = ei[e + 2];
      int pos = atomicAdd(&gcnt[(dd.z >> 2) * CPAD], 1);
      ellg[((dd.z >> 2) << 7) + pos] = (s << 2) | (dd.z & 3);
    }
    if (dd.w / SEG_SZ == seg) {
      int s = ei[e + 3];
      int pos = atomicAdd(&gcnt[(dd.w >> 2) * CPAD], 1);
      ellg[((dd.w >> 2) << 7) + pos] = (s << 2) | (dd.w & 3);
    }
  }
}

// ---- per-group bitonic sort (128 entries, 2/lane) --------------------------
// Injects the 4 self-loop entries in-register, computes degrees via ballot,
// pads -> ZROW (gather 0, add 0).

__global__ __launch_bounds__(256) void k_sort(const int* __restrict__ gcnt,
                                              int* __restrict__ ellg,
                                              float* __restrict__ dinv,
                                              float* __restrict__ ideg,
                                              float* __restrict__ sqd) {
  int w = (blockIdx.x * blockDim.x + threadIdx.x) >> 6;  // group
  int l = threadIdx.x & 63;
  int cnt = __builtin_amdgcn_readfirstlane(gcnt[w * CPAD]);  // edges only
  int tot = cnt + 4;                                     // + self loops
  int* base = ellg + ((size_t)w << 7);
  int i0 = l, i1 = 64 + l;
  int v0 = (i0 < cnt) ? base[i0]
         : (i0 < tot) ? ((((w << 2) + (i0 - cnt)) << 2) | (i0 - cnt)) : PAD_E;
  int v1 = (i1 < cnt) ? base[i1]
         : (i1 < tot) ? ((((w << 2) + (i1 - cnt)) << 2) | (i1 - cnt)) : PAD_E;

#pragma unroll
  for (int k = 2; k <= 128; k <<= 1) {
#pragma unroll
    for (int j = 64; j > 0; j >>= 1) {
      if (j >= k) continue;
      if (j == 64) {                      // in-lane pair (i, i+64); k=128 -> up
        int lo = min(v0, v1), hi = max(v0, v1);
        v0 = lo; v1 = hi;
      } else {
        int o0 = __shfl_xor(v0, j);
        int o1 = __shfl_xor(v1, j);
        bool lower = ((l & j) == 0);
        bool up0 = ((l & k) == 0);
        bool up1 = (((l + 64) & k) == 0);
        v0 = (lower == up0) ? min(v0, o0) : max(v0, o0);
        v1 = (lower == up1) ? min(v1, o1) : max(v1, o1);
      }
    }
  }

  // degrees per dst-sub via ballot (self loops included)
  int c0 = __popcll(__ballot(v0 != PAD_E && (v0 & 3) == 0)) +
           __popcll(__ballot(v1 != PAD_E && (v1 & 3) == 0));
  int c1 = __popcll(__ballot(v0 != PAD_E && (v0 & 3) == 1)) +
           __popcll(__ballot(v1 != PAD_E && (v1 & 3) == 1));
  int c2 = __popcll(__ballot(v0 != PAD_E && (v0 & 3) == 2)) +
           __popcll(__ballot(v1 != PAD_E && (v1 & 3) == 2));
  int c3 = __popcll(__ballot(v0 != PAD_E && (v0 & 3) == 3)) +
           __popcll(__ballot(v1 != PAD_E && (v1 & 3) == 3));
  if (l < 4) {
    int c = (l == 0) ? c0 : (l == 1) ? c1 : (l == 2) ? c2 : c3;
    float fc = (float)c;
    int node = (w << 2) + l;
    dinv[node] = rsqrtf(fc);
    ideg[node] = 1.0f / fc;
    sqd[node]  = sqrtf(fc);
  }

  base[l]      = (v0 == PAD_E) ? (ZROW << 2) : v0;
  base[64 + l] = (v1 == PAD_E) ? (ZROW << 2) : v1;
}

// ---- feature init: u0 = dinv * [x | 1 | 0pad], 64 cols ---------------------

__global__ void k_loadx(const float* __restrict__ x, const float* __restrict__ dinv,
                        float* __restrict__ h) {
  int i = blockIdx.x * blockDim.x + threadIdx.x;  // N*64 threads
  int nn = i >> 6, f = i & 63;
  float di = dinv[nn];
  float v = 0.f;
  if (f < F_IN) v = x[nn * F_IN + f] * di;
  else if (f == F_IN) v = di;
  h[i] = v;
}

// ---- one hop: wave per 4-node group, 8 gathers in flight -------------------
// lane = (sub: lane>>4) x (feature quad m: lane&15); variable trip count.

__global__ __launch_bounds__(256) void k_hop(const float* __restrict__ hin,
                                             float* __restrict__ hout,
                                             const int* __restrict__ gcnt,
                                             const int* __restrict__ ellg,
                                             const float* __restrict__ ideg,
                                             float* __restrict__ vsave) {
  int g = (blockIdx.x * blockDim.x + threadIdx.x) >> 6;  // group
  int lane = threadIdx.x & 63;
  int sub = lane >> 4, m = lane & 15, fo = m << 2;
  int cnt = __builtin_amdgcn_readfirstlane(gcnt[g * CPAD]);  // edges only
  int nq = (cnt + 7) >> 2;                               // + 4 self loops
  const int* base = ellg + ((size_t)g << 7);
  int rec0 = base[lane];          // slots 0..63   (coalesced 256B)
  int rec1 = base[64 + lane];     // slots 64..127
  float4 acc0 = make_float4(0.f, 0.f, 0.f, 0.f);
  float4 acc1 = acc0, acc2 = acc0, acc3 = acc0;

#define GQ(Q, EV, AV)                                                     \
  int r_##EV = ((Q) < 16) ? rec0 : rec1;                                  \
  int EV = __shfl(r_##EV, (((Q) & 15) << 2) + sub);                       \
  float4 AV = *(const float4*)(hin + (((size_t)(EV >> 2)) << 6) + fo);

#define ACCUM(EV, AV) {                                                   \
    int dd = EV & 3;                                                      \
    float m0 = (dd == 0) ? 1.f : 0.f;                                     \
    float m1 = (dd == 1) ? 1.f : 0.f;                                     \
    float m2 = (dd == 2) ? 1.f : 0.f;                                     \
    float m3 = (dd == 3) ? 1.f : 0.f;                                     \
    acc0.x = fmaf(m0, AV.x, acc0.x); acc0.y = fmaf(m0, AV.y, acc0.y);     \
    acc0.z = fmaf(m0, AV.z, acc0.z); acc0.w = fmaf(m0, AV.w, acc0.w);     \
    acc1.x = fmaf(m1, AV.x, acc1.x); acc1.y = fmaf(m1, AV.y, acc1.y);     \
    acc1.z = fmaf(m1, AV.z, acc1.z); acc1.w = fmaf(m1, AV.w, acc1.w);     \
    acc2.x = fmaf(m2, AV.x, acc2.x); acc2.y = fmaf(m2, AV.y, acc2.y);     \
    acc2.z = fmaf(m2, AV.z, acc2.z); acc2.w = fmaf(m2, AV.w, acc2.w);     \
    acc3.x = fmaf(m3, AV.x, acc3.x); acc3.y = fmaf(m3, AV.y, acc3.y);     \
    acc3.z = fmaf(m3, AV.z, acc3.z); acc3.w = fmaf(m3, AV.w, acc3.w);     \
  }

  int q = 0;
  for (; q + 8 <= nq; q += 8) {            // 8 independent 1KB gathers in flight
    GQ(q + 0, e0, a0)
    GQ(q + 1, e1, a1)
    GQ(q + 2, e2, a2)
    GQ(q + 3, e3, a3)
    GQ(q + 4, e4, a4)
    GQ(q + 5, e5, a5)
    GQ(q + 6, e6, a6)
    GQ(q + 7, e7, a7)
    ACCUM(e0, a0) ACCUM(e1, a1) ACCUM(e2, a2) ACCUM(e3, a3)
    ACCUM(e4, a4) ACCUM(e5, a5) ACCUM(e6, a6) ACCUM(e7, a7)
  }
  for (; q + 2 <= nq; q += 2) {
    GQ(q + 0, e0, a0)
    GQ(q + 1, e1, a1)
    ACCUM(e0, a0) ACCUM(e1, a1)
  }
  if (q < nq) {
    GQ(q, e0, a0)
    ACCUM(e0, a0)
  }
#undef GQ
#undef ACCUM

#define RED(A) \
  A.x += __shfl_xor(A.x, 16); A.y += __shfl_xor(A.y, 16); \
  A.z += __shfl_xor(A.z, 16); A.w += __shfl_xor(A.w, 16); \
  A.x += __shfl_xor(A.x, 32); A.y += __shfl_xor(A.y, 32); \
  A.z += __shfl_xor(A.z, 32); A.w += __shfl_xor(A.w, 32);
  RED(acc0) RED(acc1) RED(acc2) RED(acc3)
#undef RED

  float4 v = (sub == 0) ? acc0 : (sub == 1) ? acc1 : (sub == 2) ? acc2 : acc3;
  int node = (g << 2) + sub;
  float idg = ideg[node];
  v.x *= idg; v.y *= idg; v.z *= idg; v.w *= idg;
  *(float4*)(hout + (((size_t)node) << 6) + fo) = v;
  if (vsave != nullptr && m == 14) vsave[node] = v.x;  // u-space col 56
}

// ---- collapse weights: M = W1W2W3W4; c1=b1'W2W3W4; c2=b2'W3W4; c3=b3'W4+b4

__global__ void k_weights(const float* __restrict__ W1, const float* __restrict__ b1,
                          const float* __restrict__ W2, const float* __restrict__ b2,
                          const float* __restrict__ W3, const float* __restrict__ b3,
                          const float* __restrict__ W4, const float* __restrict__ b4,
                          float* __restrict__ Mw, float* __restrict__ c1,
                          float* __restrict__ c2, float* __restrict__ c3) {
  __shared__ float t1[64], t2[64], t3[64];
  int m = blockIdx.x, tid = threadIdx.x;
  if (m < F_IN) {
    if (tid < 64) {
      float a = 0.f;
      for (int k = 0; k < 64; ++k) a = fmaf(W1[m * 64 + k], W2[k * 64 + tid], a);
      t1[tid] = a;
    }
    __syncthreads();
    if (tid < 64) {
      float a = 0.f;
      for (int k = 0; k < 64; ++k) a = fmaf(t1[k], W3[k * 64 + tid], a);
      t2[tid] = a;
    }
    __syncthreads();
    {
      float a = 0.f;
      for (int k = 0; k < 64; ++k) a = fmaf(t2[k], W4[k * 256 + tid], a);
      Mw[m * 256 + tid] = a;
    }
  } else {
    if (tid < 64) {
      float a = 0.f;
      for (int k = 0; k < 64; ++k) a = fmaf(b1[k], W2[k * 64 + tid], a);
      t1[tid] = a;
    }
    __syncthreads();
    if (tid < 64) {
      float a = 0.f, b = 0.f;
      for (int k = 0; k < 64; ++k) {
        float w3 = W3[k * 64 + tid];
        a = fmaf(t1[k], w3, a);
        b = fmaf(b2[k], w3, b);
      }
      t2[tid] = a; t3[tid] = b;
    }
    __syncthreads();
    {
      float a = 0.f, b = 0.f, c = 0.f;
      for (int k = 0; k < 64; ++k) {
        float w4 = W4[k * 256 + tid];
        a = fmaf(t2[k], w4, a);
        b = fmaf(t3[k], w4, b);
        c = fmaf(b3[k], w4, c);
      }
      c1[tid] = a; c2[tid] = b; c3[tid] = c + b4[tid];
    }
  }
}

// ---- epilogue: out = (sqd*y)@M + v6*c1 + v3*c2 + c3 ------------------------
// thread j owns col j; M[:,j] in 56 VGPRs; 16 independent acc chains.

__global__ __launch_bounds__(256) void k_final(const float* __restrict__ y,
                                               const float* __restrict__ v3u,
                                               const float* __restrict__ v6u,
                                               const float* __restrict__ sqd,
                                               const float* __restrict__ Mw,
                                               const float* __restrict__ c1,
                                               const float* __restrict__ c2,
                                               const float* __restrict__ c3,
                                               float* __restrict__ out) {
  __shared__ float4 yl[NB][16];          // 4.1 KB
  __shared__ float v3l[NB], v6l[NB];
  int tid = threadIdx.x;
  int j = tid;

  float4 Mreg[14];
#pragma unroll
  for (int k4 = 0; k4 < 14; ++k4) {
    Mreg[k4].x = Mw[(k4 * 4 + 0) * F_OUT + j];
    Mreg[k4].y = Mw[(k4 * 4 + 1) * F_OUT + j];
    Mreg[k4].z = Mw[(k4 * 4 + 2) * F_OUT + j];
    Mreg[k4].w = Mw[(k4 * 4 + 3) * F_OUT + j];
  }
  float C1 = c1[j], C2 = c2[j], C3 = c3[j];

  int n0 = blockIdx.x * NB;                // N_NODES % NB == 0
  {                                        // exactly one float4 per thread
    int i = tid;
    int nn = i >> 4, q = i & 15;
    float sq = sqd[n0 + nn];
    float4 v = *(const float4*)(y + ((size_t)(n0 + nn) << 6) + q * 4);
    v.x *= sq; v.y *= sq; v.z *= sq; v.w *= sq;
    yl[nn][q] = v;
  }
  if (tid < NB) {
    float sq = sqd[n0 + tid];
    v3l[tid] = v3u[n0 + tid] * sq;
    v6l[tid] = v6u[n0 + tid] * sq;
  }
  __syncthreads();

  float acc[NB];
#pragma unroll
  for (int nn = 0; nn < NB; ++nn)
    acc[nn] = fmaf(v6l[nn], C1, fmaf(v3l[nn], C2, C3));

#pragma unroll
  for (int k4 = 0; k4 < 14; ++k4) {
    float4 mk = Mreg[k4];
#pragma unroll
    for (int nn = 0; nn < NB; ++nn) {
      float4 yv = yl[nn][k4];
      acc[nn] = fmaf(yv.w, mk.w,
                fmaf(yv.z, mk.z,
                fmaf(yv.y, mk.y,
                fmaf(yv.x, mk.x, acc[nn]))));
    }
  }

#pragma unroll
  for (int nn = 0; nn < NB; ++nn)
    out[(size_t)(n0 + nn) * F_OUT + j] = acc[nn];
}

// ---- launch ---------------------------------------------------------------

extern "C" void kernel_launch(void* const* d_in, const int* in_sizes, int n_in,
                              void* d_out, int out_size, void* d_ws, size_t ws_size,
                              hipStream_t stream) {
  const float* x  = (const float*)d_in[0];
  const int*   ei = (const int*)d_in[1];
  const float* W1 = (const float*)d_in[2];
  const float* b1 = (const float*)d_in[3];
  const float* W2 = (const float*)d_in[4];
  const float* b2 = (const float*)d_in[5];
  const float* W3 = (const float*)d_in[6];
  const float* b3 = (const float*)d_in[7];
  const float* W4 = (const float*)d_in[8];
  const float* b4 = (const float*)d_in[9];
  float* out = (float*)d_out;

  char* ws = (char*)d_ws;
  size_t off = 0;
  auto take = [&](size_t bytes) -> void* {
    void* p = ws + off;
    off += (bytes + 255) & ~(size_t)255;
    return p;
  };
  int*   gcnt  = (int*)take((size_t)N_GROUPS * CPAD * 4);         // 800 KB padded
  float* dinv  = (float*)take((size_t)N_NODES * 4);
  float* ideg  = (float*)take((size_t)N_NODES * 4);
  float* sqd   = (float*)take((size_t)N_NODES * 4);
  float* v3    = (float*)take((size_t)N_NODES * 4);
  float* v6    = (float*)take((size_t)N_NODES * 4);
  int*   ellg  = (int*)take((size_t)N_GROUPS * GSLOTS * 4);       // 6.4 MB
  float* hA    = (float*)take((size_t)(N_NODES + 1) * F_PAD * 4); // + zero row
  float* hB    = (float*)take((size_t)(N_NODES + 1) * F_PAD * 4);
  float* Mw    = (float*)take((size_t)F_IN * F_OUT * 4);
  float* c1    = (float*)take((size_t)F_OUT * 4);
  float* c2    = (float*)take((size_t)F_OUT * 4);
  float* c3    = (float*)take((size_t)F_OUT * 4);

  (void)hipMemsetAsync(gcnt, 0, (size_t)N_GROUPS * CPAD * 4, stream);
  (void)hipMemsetAsync(hA + (size_t)ZROW * F_PAD, 0, F_PAD * 4, stream);
  (void)hipMemsetAsync(hB + (size_t)ZROW * F_PAD, 0, F_PAD * 4, stream);
  k_fill<<<1024, 256, 0, stream>>>(ei, gcnt, ellg);
  k_sort<<<(N_GROUPS * 64) / 256, 256, 0, stream>>>(gcnt, ellg, dinv, ideg, sqd);
  k_loadx<<<(N_NODES * F_PAD) / 256, 256, 0, stream>>>(x, dinv, hA);
  k_weights<<<F_IN + 1, 256, 0, stream>>>(W1, b1, W2, b2, W3, b3, W4, b4, Mw, c1, c2, c3);

  float* src = hA;
  float* dst = hB;
  for (int hop = 1; hop <= 9; ++hop) {
    float* vs = (hop == 3) ? v3 : (hop == 6) ? v6 : nullptr;
    k_hop<<<(N_GROUPS * 64) / 256, 256, 0, stream>>>(src, dst, gcnt, ellg, ideg, vs);
    float* t = src; src = dst; dst = t;
  }
  k_final<<<N_NODES / NB, 256, 0, stream>>>(src, v3, v6, sqd, Mw, c1, c2, c3, out);
}